// Round 18
// baseline (403.644 us; speedup 1.0000x reference)
//
#include <hip/hip_runtime.h>
#include <hip/hip_fp16.h>

#define TPB 256
#define STPB 1024  // wide-block size for streaming kernels
#define TILE 8192  // items per split tile
#define FCAP 9216  // finalize LDS span capacity

__device__ __forceinline__ float leaky02(float x){ return x > 0.f ? x : 0.2f*x; }
__device__ __forceinline__ unsigned pack_h2(float a, float b){
  return (unsigned)__half_as_ushort(__float2half_rn(a)) |
         ((unsigned)__half_as_ushort(__float2half_rn(b)) << 16);
}

// ---------------- hierarchical exclusive scan (out-of-place: counts preserved) ----------------
__global__ void k_scan_tile(const int* __restrict__ in, int* __restrict__ out,
                            int* __restrict__ bsum, int n) {
  __shared__ int sh[TPB];
  int t = threadIdx.x;
  int base = blockIdx.x * (TPB*4) + t*4;
  int v0=0,v1=0,v2=0,v3=0;
  if (base+0 < n) v0 = in[base+0];
  if (base+1 < n) v1 = in[base+1];
  if (base+2 < n) v2 = in[base+2];
  if (base+3 < n) v3 = in[base+3];
  int tsum = v0+v1+v2+v3;
  sh[t] = tsum; __syncthreads();
  for (int off=1; off<TPB; off<<=1){
    int x = (t>=off) ? sh[t-off] : 0;
    __syncthreads();
    sh[t] += x;
    __syncthreads();
  }
  int incl = sh[t];
  int excl = incl - tsum;
  if (t == TPB-1) bsum[blockIdx.x] = incl;
  int run = excl;
  if (base+0 < n){ out[base+0] = run; run += v0; }
  if (base+1 < n){ out[base+1] = run; run += v1; }
  if (base+2 < n){ out[base+2] = run; run += v2; }
  if (base+3 < n){ out[base+3] = run; run += v3; }
}

__global__ void k_scan_small(int* __restrict__ a, int n) {
  __shared__ int sh[TPB];
  __shared__ int carry;
  int t = threadIdx.x;
  if (t==0) carry = 0;
  __syncthreads();
  for (int base=0; base<n; base+=TPB){
    int v = (base+t < n) ? a[base+t] : 0;
    sh[t] = v; __syncthreads();
    for (int off=1; off<TPB; off<<=1){
      int x = (t>=off)? sh[t-off]:0; __syncthreads();
      sh[t]+=x; __syncthreads();
    }
    int c0 = carry;
    if (base+t < n) a[base+t] = c0 + sh[t] - v;
    int tot = sh[TPB-1];
    __syncthreads();
    if (t==0) carry = c0 + tot;
    __syncthreads();
  }
}

__global__ void k_scan_add(int* __restrict__ out, const int* __restrict__ bsum,
                           int n, int total) {
  int i = blockIdx.x*TPB + threadIdx.x;
  if (i < n) out[i] += bsum[i >> 10];
  if (i == 0) out[n] = total;
}

// ---------------- split phase 1: per-tile histogram (LDS only) ----------------
__global__ __launch_bounds__(STPB) void k_split_hist(
    const int* __restrict__ key, int n, int shift, int T,
    int* __restrict__ hist, int nbc){
  __shared__ int cnt[512];
  int b = blockIdx.x, t = threadIdx.x;
  for (int k=t;k<nbc;k+=STPB) cnt[k]=0;
  __syncthreads();
  int i0 = b*TILE, end = min(n, i0+TILE);
  for (int i=i0+t; i<end; i+=STPB) atomicAdd(&cnt[key[i]>>shift], 1);
  __syncthreads();
  for (int k=t;k<nbc;k+=STPB) hist[(size_t)k*T + b] = cnt[k];
}

// ---- split phase 2: LDS-staged scatter; counts from hist, bases from hist2 ----
__global__ __launch_bounds__(STPB) void k_split_scatter_edges(
    const int* __restrict__ src, const int* __restrict__ dst,
    const float* __restrict__ eattr, int E, int T,
    const int* __restrict__ hist, const int* __restrict__ hist2,
    int2* __restrict__ tmp, int nbc){
  __shared__ int lcur[512];
  __shared__ int lbase[512];
  __shared__ int gbase[512];
  __shared__ int sh[256];
  __shared__ int carry_s;
  __shared__ int2 buf[TILE];       // 64 KB
  int b = blockIdx.x, t = threadIdx.x;
  if (t < 512){
    int c = (t < nbc) ? hist[(size_t)t*T + b] : 0;
    lcur[t] = c;
    gbase[t] = (t < nbc) ? hist2[(size_t)t*T + b] : 0;
  }
  __syncthreads();
  int v0 = 0;
  if (t < 256){ v0 = lcur[t]; sh[t] = v0; }
  __syncthreads();
  for (int off=1; off<256; off<<=1){
    int x = 0;
    if (t < 256 && t >= off) x = sh[t-off];
    __syncthreads();
    if (t < 256) sh[t] += x;
    __syncthreads();
  }
  if (t < 256) lbase[t] = sh[t] - v0;
  if (t == 255) carry_s = sh[255];
  __syncthreads();
  int v1 = 0;
  if (t < 256){ v1 = lcur[256+t]; sh[t] = v1; }
  __syncthreads();
  for (int off=1; off<256; off<<=1){
    int x = 0;
    if (t < 256 && t >= off) x = sh[t-off];
    __syncthreads();
    if (t < 256) sh[t] += x;
    __syncthreads();
  }
  if (t < 256) lbase[256+t] = carry_s + sh[t] - v1;
  __syncthreads();
  if (t < 512) lcur[t] = lbase[t];
  __syncthreads();
  int i0 = b*TILE, end = min(E, i0+TILE);
  for (int i=i0+t; i<end; i+=STPB){
    int d = dst[i];
    int k = d>>8;
    int pos = atomicAdd(&lcur[k], 1);
    float2 ea = ((const float2*)eattr)[i];
    buf[pos] = make_int2(src[i] | ((d & 255)<<17), (int)pack_h2(ea.x, ea.y));
  }
  __syncthreads();
  int wave = t >> 6, lane = t & 63;
  for (int k=wave; k<nbc; k+=STPB/64){
    int s = lbase[k];
    int c = lcur[k] - s;
    int g = gbase[k];
    for (int i=lane; i<c; i+=64) tmp[g+i] = buf[s+i];
  }
}

__global__ __launch_bounds__(STPB) void k_split_scatter_pool(
    const int* __restrict__ rows, const int* __restrict__ cols,
    const float* __restrict__ vals, int n, int T,
    const int* __restrict__ hist, const int* __restrict__ hist2,
    int2* __restrict__ tmp, int nbc){
  __shared__ int lcur[512];
  __shared__ int lbase[512];
  __shared__ int gbase[512];
  __shared__ int sh[256];
  __shared__ int carry_s;
  __shared__ int2 buf[TILE];       // 64 KB
  int b = blockIdx.x, t = threadIdx.x;
  if (t < 512){
    int c = (t < nbc) ? hist[(size_t)t*T + b] : 0;
    lcur[t] = c;
    gbase[t] = (t < nbc) ? hist2[(size_t)t*T + b] : 0;
  }
  __syncthreads();
  int v0 = 0;
  if (t < 256){ v0 = lcur[t]; sh[t] = v0; }
  __syncthreads();
  for (int off=1; off<256; off<<=1){
    int x = 0;
    if (t < 256 && t >= off) x = sh[t-off];
    __syncthreads();
    if (t < 256) sh[t] += x;
    __syncthreads();
  }
  if (t < 256) lbase[t] = sh[t] - v0;
  if (t == 255) carry_s = sh[255];
  __syncthreads();
  int v1 = 0;
  if (t < 256){ v1 = lcur[256+t]; sh[t] = v1; }
  __syncthreads();
  for (int off=1; off<256; off<<=1){
    int x = 0;
    if (t < 256 && t >= off) x = sh[t-off];
    __syncthreads();
    if (t < 256) sh[t] += x;
    __syncthreads();
  }
  if (t < 256) lbase[256+t] = carry_s + sh[t] - v1;
  __syncthreads();
  if (t < 512) lcur[t] = lbase[t];
  __syncthreads();
  int i0 = b*TILE, end = min(n, i0+TILE);
  for (int i=i0+t; i<end; i+=STPB){
    int r = rows[i];
    int k = r>>9;
    int pos = atomicAdd(&lcur[k], 1);
    buf[pos] = make_int2(cols[i] | ((r & 511)<<17), __float_as_int(vals[i]));
  }
  __syncthreads();
  int wave = t >> 6, lane = t & 63;
  for (int k=wave; k<nbc; k+=STPB/64){
    int s = lbase[k];
    int c = lcur[k] - s;
    int g = gbase[k];
    for (int i=lane; i<c; i+=64) tmp[g+i] = buf[s+i];
  }
}

// ---- finalize edges: single-pass via LDS span (fallback if oversize) ----
__global__ __launch_bounds__(STPB) void k_finalize_edges(
    const int2* __restrict__ tmp, const int* __restrict__ hist2, int T, int E,
    int N, int* __restrict__ rs, int2* __restrict__ rec){
  __shared__ int cnt[256];
  __shared__ int sh[256];
  __shared__ int2 fbuf[FCAP];      // 72 KB
  int b = blockIdx.x, t = threadIdx.x;
  int base = hist2[(size_t)b*T];
  int endv = (b+1 < (int)gridDim.x) ? hist2[(size_t)(b+1)*T] : E;
  int size = endv - base;
  bool fits = (size <= FCAP);
  if (t < 256) cnt[t] = 0;
  __syncthreads();
  if (fits){
    for (int i=t; i<size; i+=STPB) fbuf[i] = tmp[base+i];
    __syncthreads();
    for (int i=t; i<size; i+=STPB) atomicAdd(&cnt[(((unsigned)fbuf[i].x)>>17)&255], 1);
  } else {
    for (int i=t; i<size; i+=STPB) atomicAdd(&cnt[(((unsigned)tmp[base+i].x)>>17)&255], 1);
  }
  __syncthreads();
  int v = 0;
  if (t < 256){ v = cnt[t]; sh[t] = v; }
  __syncthreads();
  for (int off=1; off<256; off<<=1){
    int x = 0;
    if (t < 256 && t >= off) x = sh[t-off];
    __syncthreads();
    if (t < 256) sh[t] += x;
    __syncthreads();
  }
  if (t < 256){
    int excl = sh[t] - v;
    int d = (b<<8)+t;
    if (d<=N) rs[d] = base + excl;
    cnt[t] = excl;
  }
  __syncthreads();
  if (fits){
    for (int i=t; i<size; i+=STPB){
      int2 q = fbuf[i];
      int k = (((unsigned)q.x)>>17)&255;
      int p = atomicAdd(&cnt[k],1);
      rec[base+p] = make_int2(q.x & 0x1FFFF, q.y);
    }
  } else {
    for (int i=t; i<size; i+=STPB){
      int2 q = tmp[base+i];
      int k = (((unsigned)q.x)>>17)&255;
      int p = atomicAdd(&cnt[k],1);
      rec[base+p] = make_int2(q.x & 0x1FFFF, q.y);
    }
  }
}

// ---- mattr: quad-per-node sweep over sorted CSR span (no atomics) ----
__global__ __launch_bounds__(TPB) void k_mattr(
    const int2* __restrict__ rec, const int* __restrict__ rs,
    float2* __restrict__ mattr, int N){
  int n = blockIdx.x*(TPB/4) + (threadIdx.x>>2);
  if (n >= N) return;
  int l4 = threadIdx.x & 3;
  int jb = rs[n], je = rs[n+1];
  float sx = 0.f, sy = 0.f;
  for (int j = jb + l4; j < je; j += 4){
    float2 ea = __half22float2(*(const __half2*)&rec[j].y);
    sx += ea.x; sy += ea.y;
  }
  sx += __shfl_xor(sx, 1); sx += __shfl_xor(sx, 2);
  sy += __shfl_xor(sy, 1); sy += __shfl_xor(sy, 2);
  if (l4 == 0){
    int cn = je - jb;
    float inv = 1.0f/(float)(cn > 0 ? cn : 1);
    mattr[n] = make_float2(sx*inv, sy*inv);
  }
}

// ---- finalize pool: single-pass via LDS span (fallback if oversize) ----
__global__ __launch_bounds__(STPB) void k_finalize_pool(
    const int2* __restrict__ tmp, const int* __restrict__ hist2, int T, int NNZ,
    int P, int* __restrict__ rs, int2* __restrict__ rec){
  __shared__ int cnt[512];
  __shared__ int sh[256];
  __shared__ int carry_s;
  __shared__ int2 fbuf[FCAP];      // 72 KB
  int b = blockIdx.x, t = threadIdx.x;
  int base = hist2[(size_t)b*T];
  int endv = (b+1 < (int)gridDim.x) ? hist2[(size_t)(b+1)*T] : NNZ;
  int size = endv - base;
  bool fits = (size <= FCAP);
  if (t < 512) cnt[t] = 0;
  __syncthreads();
  if (fits){
    for (int i=t;i<size;i+=STPB) fbuf[i] = tmp[base+i];
    __syncthreads();
    for (int i=t;i<size;i+=STPB) atomicAdd(&cnt[(((unsigned)fbuf[i].x)>>17)&511], 1);
  } else {
    for (int i=t;i<size;i+=STPB) atomicAdd(&cnt[(((unsigned)tmp[base+i].x)>>17)&511], 1);
  }
  __syncthreads();
  int excl0 = 0, excl1 = 0;
  int v0 = 0;
  if (t < 256){ v0 = cnt[t]; sh[t] = v0; }
  __syncthreads();
  for (int off=1; off<256; off<<=1){
    int x = 0;
    if (t < 256 && t >= off) x = sh[t-off];
    __syncthreads();
    if (t < 256) sh[t] += x;
    __syncthreads();
  }
  if (t < 256) excl0 = sh[t] - v0;
  if (t == 255) carry_s = sh[255];
  __syncthreads();
  int v1 = 0;
  if (t < 256){ v1 = cnt[256+t]; sh[t] = v1; }
  __syncthreads();
  for (int off=1; off<256; off<<=1){
    int x = 0;
    if (t < 256 && t >= off) x = sh[t-off];
    __syncthreads();
    if (t < 256) sh[t] += x;
    __syncthreads();
  }
  if (t < 256) excl1 = carry_s + sh[t] - v1;
  __syncthreads();
  if (t < 256){
    cnt[t] = excl0; cnt[256+t] = excl1;
    int r0 = (b<<9)+t;
    if (r0<=P) rs[r0] = base+excl0;
    int r1 = r0+256;
    if (r1<=P) rs[r1] = base+excl1;
  }
  __syncthreads();
  if (fits){
    for (int i=t;i<size;i+=STPB){
      int2 q = fbuf[i];
      int k = (((unsigned)q.x)>>17)&511;
      int p = atomicAdd(&cnt[k],1);
      rec[base+p] = make_int2(q.x & 0x1FFFF, q.y);
    }
  } else {
    for (int i=t;i<size;i+=STPB){
      int2 q = tmp[base+i];
      int k = (((unsigned)q.x)>>17)&511;
      int p = atomicAdd(&cnt[k],1);
      rec[base+p] = make_int2(q.x & 0x1FFFF, q.y);
    }
  }
}

// ---------------- effective edge weights: weff[l*4 + h*2 + {0,1}] ----------------
__global__ void k_weff(const float* __restrict__ ew1, const float* __restrict__ ae1,
                       const float* __restrict__ ew2, const float* __restrict__ ae2,
                       const float* __restrict__ ew3, const float* __restrict__ ae3,
                       float* __restrict__ weff){
  int t = threadIdx.x;
  if (t >= 6) return;
  int l = t>>1, h = t&1;
  const float* ew = l==0?ew1:(l==1?ew2:ew3);
  const float* ae = l==0?ae1:(l==1?ae2:ae3);
  float w0=0.f, w1=0.f;
  for (int c=0;c<16;c++){
    float a = ae[h*16+c];
    w0 += ew[h*16+c]*a;
    w1 += ew[32+h*16+c]*a;
  }
  weff[l*4+h*2]   = w0;
  weff[l*4+h*2+1] = w1;
}

// ---------------- per-node transform: xp16 = f16(x@W), a_src, a_dst ----------------
__global__ __launch_bounds__(TPB) void k_node_pre1(
    const int* __restrict__ gid, const float* __restrict__ ord, const float* __restrict__ emb,
    const float* __restrict__ lin_w, const float* __restrict__ att_src, const float* __restrict__ att_dst,
    __half* __restrict__ xp16, float* __restrict__ asrc, float* __restrict__ adst, int N){
  __shared__ float W[20*32];
  __shared__ float As[32], Ad[32];
  for (int i=threadIdx.x; i<20*32; i+=TPB) W[i]=lin_w[i];
  if (threadIdx.x < 32){ As[threadIdx.x]=att_src[threadIdx.x]; Ad[threadIdx.x]=att_dst[threadIdx.x]; }
  __syncthreads();
  int n = blockIdx.x*TPB+threadIdx.x;
  if (n>=N) return;
  float x[20];
  int g = gid[n];
  #pragma unroll
  for (int k=0;k<16;k++) x[k]=emb[g*16+k];
  float4 o4 = ((const float4*)ord)[n];
  x[16]=o4.x; x[17]=o4.y; x[18]=o4.z; x[19]=o4.w;
  float acc[32];
  #pragma unroll
  for (int c=0;c<32;c++) acc[c]=0.f;
  #pragma unroll
  for (int k=0;k<20;k++){
    float xk=x[k];
    #pragma unroll
    for (int c=0;c<32;c++) acc[c] += xk*W[k*32+c];
  }
  float s0=0,s1=0,d0=0,d1=0;
  #pragma unroll
  for (int c=0;c<16;c++){
    s0+=acc[c]*As[c];      d0+=acc[c]*Ad[c];
    s1+=acc[16+c]*As[16+c]; d1+=acc[16+c]*Ad[16+c];
  }
  unsigned us[16];
  #pragma unroll
  for (int k=0;k<16;k++) us[k] = pack_h2(acc[2*k], acc[2*k+1]);
  uint4* o = (uint4*)(xp16 + (size_t)n*32);
  o[0]=make_uint4(us[0],us[1],us[2],us[3]);
  o[1]=make_uint4(us[4],us[5],us[6],us[7]);
  o[2]=make_uint4(us[8],us[9],us[10],us[11]);
  o[3]=make_uint4(us[12],us[13],us[14],us[15]);
  asrc[2*n]=s0; asrc[2*n+1]=s1; adst[2*n]=d0; adst[2*n+1]=d1;
}

// f16-input variant: reads h from f16 buffer
__global__ __launch_bounds__(TPB) void k_node_pre16(
    const __half* __restrict__ hin,
    const float* __restrict__ lin_w, const float* __restrict__ att_src, const float* __restrict__ att_dst,
    __half* __restrict__ xp16, float* __restrict__ asrc, float* __restrict__ adst, int N){
  __shared__ float W[32*32];
  __shared__ float As[32], Ad[32];
  for (int i=threadIdx.x; i<1024; i+=TPB) W[i]=lin_w[i];
  if (threadIdx.x < 32){ As[threadIdx.x]=att_src[threadIdx.x]; Ad[threadIdx.x]=att_dst[threadIdx.x]; }
  __syncthreads();
  int n = blockIdx.x*TPB+threadIdx.x;
  if (n>=N) return;
  float x[32];
  const uint4* hi = (const uint4*)(hin + (size_t)n*32);
  #pragma unroll
  for (int q=0;q<4;q++){
    uint4 u = hi[q];
    float2 f;
    f=__half22float2(*(const __half2*)&u.x); x[q*8+0]=f.x; x[q*8+1]=f.y;
    f=__half22float2(*(const __half2*)&u.y); x[q*8+2]=f.x; x[q*8+3]=f.y;
    f=__half22float2(*(const __half2*)&u.z); x[q*8+4]=f.x; x[q*8+5]=f.y;
    f=__half22float2(*(const __half2*)&u.w); x[q*8+6]=f.x; x[q*8+7]=f.y;
  }
  float acc[32];
  #pragma unroll
  for (int c=0;c<32;c++) acc[c]=0.f;
  #pragma unroll
  for (int k=0;k<32;k++){
    float xk=x[k];
    #pragma unroll
    for (int c=0;c<32;c++) acc[c] += xk*W[k*32+c];
  }
  float s0=0,s1=0,d0=0,d1=0;
  #pragma unroll
  for (int c=0;c<16;c++){
    s0+=acc[c]*As[c];       d0+=acc[c]*Ad[c];
    s1+=acc[16+c]*As[16+c]; d1+=acc[16+c]*Ad[16+c];
  }
  unsigned us[16];
  #pragma unroll
  for (int k=0;k<16;k++) us[k] = pack_h2(acc[2*k], acc[2*k+1]);
  uint4* o = (uint4*)(xp16 + (size_t)n*32);
  o[0]=make_uint4(us[0],us[1],us[2],us[3]);
  o[1]=make_uint4(us[4],us[5],us[6],us[7]);
  o[2]=make_uint4(us[8],us[9],us[10],us[11]);
  o[3]=make_uint4(us[12],us[13],us[14],us[15]);
  asrc[2*n]=s0; asrc[2*n+1]=s1; adst[2*n]=d0; adst[2*n+1]=d1;
}

// ---- GAT aggregation: 4 nodes/wave x 4 quads/node, 4-deep pipeline, f16 output ----
__global__ __launch_bounds__(TPB) void k_agg(
    const __half* __restrict__ xp16, const float* __restrict__ asrc, const float* __restrict__ adst,
    const int* __restrict__ rs, const int2* __restrict__ rec,
    const float2* __restrict__ mattr,
    const float* __restrict__ weff_l,
    const float* __restrict__ bias, __half* __restrict__ hout16, int N)
{
  int lane = threadIdx.x & 63;
  int node_slot = lane >> 4;          // 4 nodes per wave
  int n = blockIdx.x*16 + (threadIdx.x>>6)*4 + node_slot;
  if (n >= N) return;                 // whole 16-lane group exits together
  int sub = (lane >> 2) & 3;          // 4 quads per node
  int l4  = lane & 3;                 // owns channels l4*8 .. l4*8+7
  int h   = l4 >> 1;
  float2 wv = ((const float2*)weff_l)[h];
  float adn = adst[2*n+h];
  float ax0=0,ay0=0,ax1=0,ay1=0,ax2=0,ay2=0,ax3=0,ay3=0;
  float den=0.f;
  int jb = rs[n], je = rs[n+1];
  int j = jb + sub;
  // 4 edges per iteration: all row loads issued before dependent math
  for (; j + 12 < je; j += 16){
    int2 r1 = rec[j];
    int2 r2 = rec[j+4];
    int2 r3 = rec[j+8];
    int2 r4 = rec[j+12];
    uint4 u1 = ((const uint4*)(xp16 + (size_t)r1.x*32))[l4];
    uint4 u2 = ((const uint4*)(xp16 + (size_t)r2.x*32))[l4];
    uint4 u3 = ((const uint4*)(xp16 + (size_t)r3.x*32))[l4];
    uint4 u4 = ((const uint4*)(xp16 + (size_t)r4.x*32))[l4];
    float as1 = asrc[2*r1.x+h];
    float as2 = asrc[2*r2.x+h];
    float as3 = asrc[2*r3.x+h];
    float as4 = asrc[2*r4.x+h];
    float2 e1 = __half22float2(*(const __half2*)&r1.y);
    float2 e2 = __half22float2(*(const __half2*)&r2.y);
    float2 e3 = __half22float2(*(const __half2*)&r3.y);
    float2 e4 = __half22float2(*(const __half2*)&r4.y);
    float p1 = __expf(leaky02(as1 + adn + e1.x*wv.x + e1.y*wv.y));
    float p2 = __expf(leaky02(as2 + adn + e2.x*wv.x + e2.y*wv.y));
    float p3 = __expf(leaky02(as3 + adn + e3.x*wv.x + e3.y*wv.y));
    float p4 = __expf(leaky02(as4 + adn + e4.x*wv.x + e4.y*wv.y));
    float2 f;
    f=__half22float2(*(const __half2*)&u1.x); ax0+=p1*f.x; ay0+=p1*f.y;
    f=__half22float2(*(const __half2*)&u1.y); ax1+=p1*f.x; ay1+=p1*f.y;
    f=__half22float2(*(const __half2*)&u1.z); ax2+=p1*f.x; ay2+=p1*f.y;
    f=__half22float2(*(const __half2*)&u1.w); ax3+=p1*f.x; ay3+=p1*f.y;
    f=__half22float2(*(const __half2*)&u2.x); ax0+=p2*f.x; ay0+=p2*f.y;
    f=__half22float2(*(const __half2*)&u2.y); ax1+=p2*f.x; ay1+=p2*f.y;
    f=__half22float2(*(const __half2*)&u2.z); ax2+=p2*f.x; ay2+=p2*f.y;
    f=__half22float2(*(const __half2*)&u2.w); ax3+=p2*f.x; ay3+=p2*f.y;
    f=__half22float2(*(const __half2*)&u3.x); ax0+=p3*f.x; ay0+=p3*f.y;
    f=__half22float2(*(const __half2*)&u3.y); ax1+=p3*f.x; ay1+=p3*f.y;
    f=__half22float2(*(const __half2*)&u3.z); ax2+=p3*f.x; ay2+=p3*f.y;
    f=__half22float2(*(const __half2*)&u3.w); ax3+=p3*f.x; ay3+=p3*f.y;
    f=__half22float2(*(const __half2*)&u4.x); ax0+=p4*f.x; ay0+=p4*f.y;
    f=__half22float2(*(const __half2*)&u4.y); ax1+=p4*f.x; ay1+=p4*f.y;
    f=__half22float2(*(const __half2*)&u4.z); ax2+=p4*f.x; ay2+=p4*f.y;
    f=__half22float2(*(const __half2*)&u4.w); ax3+=p4*f.x; ay3+=p4*f.y;
    den += p1 + p2 + p3 + p4;
  }
  for (; j < je; j += 4){
    int2 r1 = rec[j];
    uint4 u1 = ((const uint4*)(xp16 + (size_t)r1.x*32))[l4];
    float as1 = asrc[2*r1.x+h];
    float2 e1 = __half22float2(*(const __half2*)&r1.y);
    float p1 = __expf(leaky02(as1 + adn + e1.x*wv.x + e1.y*wv.y));
    float2 f;
    f=__half22float2(*(const __half2*)&u1.x); ax0+=p1*f.x; ay0+=p1*f.y;
    f=__half22float2(*(const __half2*)&u1.y); ax1+=p1*f.x; ay1+=p1*f.y;
    f=__half22float2(*(const __half2*)&u1.z); ax2+=p1*f.x; ay2+=p1*f.y;
    f=__half22float2(*(const __half2*)&u1.w); ax3+=p1*f.x; ay3+=p1*f.y;
    den += p1;
  }
  #pragma unroll
  for (int m=4; m<16; m<<=1){
    ax0+=__shfl_xor(ax0,m); ay0+=__shfl_xor(ay0,m);
    ax1+=__shfl_xor(ax1,m); ay1+=__shfl_xor(ay1,m);
    ax2+=__shfl_xor(ax2,m); ay2+=__shfl_xor(ay2,m);
    ax3+=__shfl_xor(ax3,m); ay3+=__shfl_xor(ay3,m);
    den+=__shfl_xor(den,m);
  }
  if (sub == 0){
    float2 ma = mattr[n];
    float al = leaky02(asrc[2*n+h] + adn + ma.x*wv.x + ma.y*wv.y);
    float p = __expf(al);
    uint4 u = ((const uint4*)(xp16 + (size_t)n*32))[l4];
    float2 f0 = __half22float2(*(const __half2*)&u.x);
    float2 f1 = __half22float2(*(const __half2*)&u.y);
    float2 f2 = __half22float2(*(const __half2*)&u.z);
    float2 f3 = __half22float2(*(const __half2*)&u.w);
    ax0 += p*f0.x; ay0 += p*f0.y;
    ax1 += p*f1.x; ay1 += p*f1.y;
    ax2 += p*f2.x; ay2 += p*f2.y;
    ax3 += p*f3.x; ay3 += p*f3.y;
    den += p;
    float dinv = 1.0f/(den + 1e-16f);
    float4 b0 = ((const float4*)bias)[l4*2];
    float4 b1 = ((const float4*)bias)[l4*2+1];
    float o0 = fmaxf(ax0*dinv + b0.x, 0.f);
    float o1 = fmaxf(ay0*dinv + b0.y, 0.f);
    float o2 = fmaxf(ax1*dinv + b0.z, 0.f);
    float o3 = fmaxf(ay1*dinv + b0.w, 0.f);
    float o4 = fmaxf(ax2*dinv + b1.x, 0.f);
    float o5 = fmaxf(ay2*dinv + b1.y, 0.f);
    float o6 = fmaxf(ax3*dinv + b1.z, 0.f);
    float o7 = fmaxf(ay3*dinv + b1.w, 0.f);
    ((uint4*)(hout16 + (size_t)n*32))[l4] =
      make_uint4(pack_h2(o0,o1), pack_h2(o2,o3), pack_h2(o4,o5), pack_h2(o6,o7));
  }
}

// ---------------- pooling: QUAD per row, 4-deep pipelined serial accumulate ----------------
__global__ __launch_bounds__(TPB) void k_pool_q(
    const __half* __restrict__ h3, const int* __restrict__ rsP,
    const int2* __restrict__ rec, float* __restrict__ pooled, int P){
  int p = blockIdx.x*(TPB/4) + (threadIdx.x>>2);
  if (p >= P) return;
  int l4 = threadIdx.x & 3;
  float ax0=0,ay0=0,ax1=0,ay1=0,ax2=0,ay2=0,ax3=0,ay3=0;
  int jb = rsP[p], je = rsP[p+1];
  int j = jb;
  for (; j+3 < je; j += 4){
    int2 q1 = rec[j];
    int2 q2 = rec[j+1];
    int2 q3 = rec[j+2];
    int2 q4 = rec[j+3];
    uint4 u1 = ((const uint4*)(h3 + (size_t)q1.x*32))[l4];
    uint4 u2 = ((const uint4*)(h3 + (size_t)q2.x*32))[l4];
    uint4 u3 = ((const uint4*)(h3 + (size_t)q3.x*32))[l4];
    uint4 u4 = ((const uint4*)(h3 + (size_t)q4.x*32))[l4];
    float v1 = __int_as_float(q1.y);
    float v2 = __int_as_float(q2.y);
    float v3 = __int_as_float(q3.y);
    float v4 = __int_as_float(q4.y);
    float2 f;
    f=__half22float2(*(const __half2*)&u1.x); ax0+=v1*f.x; ay0+=v1*f.y;
    f=__half22float2(*(const __half2*)&u1.y); ax1+=v1*f.x; ay1+=v1*f.y;
    f=__half22float2(*(const __half2*)&u1.z); ax2+=v1*f.x; ay2+=v1*f.y;
    f=__half22float2(*(const __half2*)&u1.w); ax3+=v1*f.x; ay3+=v1*f.y;
    f=__half22float2(*(const __half2*)&u2.x); ax0+=v2*f.x; ay0+=v2*f.y;
    f=__half22float2(*(const __half2*)&u2.y); ax1+=v2*f.x; ay1+=v2*f.y;
    f=__half22float2(*(const __half2*)&u2.z); ax2+=v2*f.x; ay2+=v2*f.y;
    f=__half22float2(*(const __half2*)&u2.w); ax3+=v2*f.x; ay3+=v2*f.y;
    f=__half22float2(*(const __half2*)&u3.x); ax0+=v3*f.x; ay0+=v3*f.y;
    f=__half22float2(*(const __half2*)&u3.y); ax1+=v3*f.x; ay1+=v3*f.y;
    f=__half22float2(*(const __half2*)&u3.z); ax2+=v3*f.x; ay2+=v3*f.y;
    f=__half22float2(*(const __half2*)&u3.w); ax3+=v3*f.x; ay3+=v3*f.y;
    f=__half22float2(*(const __half2*)&u4.x); ax0+=v4*f.x; ay0+=v4*f.y;
    f=__half22float2(*(const __half2*)&u4.y); ax1+=v4*f.x; ay1+=v4*f.y;
    f=__half22float2(*(const __half2*)&u4.z); ax2+=v4*f.x; ay2+=v4*f.y;
    f=__half22float2(*(const __half2*)&u4.w); ax3+=v4*f.x; ay3+=v4*f.y;
  }
  for (; j < je; ++j){
    int2 q1 = rec[j];
    uint4 u1 = ((const uint4*)(h3 + (size_t)q1.x*32))[l4];
    float v1 = __int_as_float(q1.y);
    float2 f;
    f=__half22float2(*(const __half2*)&u1.x); ax0+=v1*f.x; ay0+=v1*f.y;
    f=__half22float2(*(const __half2*)&u1.y); ax1+=v1*f.x; ay1+=v1*f.y;
    f=__half22float2(*(const __half2*)&u1.z); ax2+=v1*f.x; ay2+=v1*f.y;
    f=__half22float2(*(const __half2*)&u1.w); ax3+=v1*f.x; ay3+=v1*f.y;
  }
  float4* o = (float4*)(pooled + (size_t)p*32);
  o[l4*2]   = make_float4(ax0,ay0,ax1,ay1);
  o[l4*2+1] = make_float4(ax2,ay2,ax3,ay3);
}

// ---------------- MLP head: thread per row ----------------
__global__ __launch_bounds__(TPB) void k_head(
    const float* __restrict__ pooled,
    const float* __restrict__ W1, const float* __restrict__ b1,
    const float* __restrict__ W2, const float* __restrict__ b2,
    float* __restrict__ out, int P){
  __shared__ float sW1[32*32];
  __shared__ float sb1[32], sW2[32];
  for (int i=threadIdx.x;i<1024;i+=TPB) sW1[i]=W1[i];
  if (threadIdx.x<32){ sb1[threadIdx.x]=b1[threadIdx.x]; sW2[threadIdx.x]=W2[threadIdx.x]; }
  __syncthreads();
  int p = blockIdx.x*TPB + threadIdx.x;
  if (p >= P) return;
  float x[32];
  const float4* pi = (const float4*)(pooled + (size_t)p*32);
  #pragma unroll
  for (int q=0;q<8;q++){ float4 v=pi[q]; x[4*q]=v.x; x[4*q+1]=v.y; x[4*q+2]=v.z; x[4*q+3]=v.w; }
  float r = 0.f;
  #pragma unroll
  for (int c=0;c<32;c++){
    float hh = sb1[c];
    #pragma unroll
    for (int k=0;k<32;k++) hh += x[k]*sW1[k*32+c];
    r += fmaxf(hh, 0.f) * sW2[c];
  }
  out[p] = r + b2[0];
}

// ---------------- launch ----------------
extern "C" void kernel_launch(void* const* d_in, const int* in_sizes, int n_in,
                              void* d_out, int out_size, void* d_ws, size_t ws_size,
                              hipStream_t stream){
  const int*   group_ids = (const int*)d_in[0];
  const float* ord       = (const float*)d_in[1];
  const int*   eidx      = (const int*)d_in[2];
  const float* eattr     = (const float*)d_in[3];
  const int*   prow      = (const int*)d_in[4];
  const int*   pcol      = (const int*)d_in[5];
  const float* pval      = (const float*)d_in[6];
  const float* emb       = (const float*)d_in[8];
  const float* head_w1   = (const float*)d_in[27];
  const float* head_b1   = (const float*)d_in[28];
  const float* head_w2   = (const float*)d_in[29];
  const float* head_b2   = (const float*)d_in[30];

  int N   = in_sizes[0];
  int E   = in_sizes[2]/2;
  int NNZ = in_sizes[4];
  int P   = out_size;

  const int* src = eidx;
  const int* dst = eidx + E;

  int NBC_E = (N+255)>>8;
  int T_E   = (E + TILE-1)/TILE;
  int nHistE = NBC_E*T_E;
  int NBC_P = (P+511)>>9;
  int T_P   = (NNZ + TILE-1)/TILE;
  int nHistP = NBC_P*T_P;
  int nHistMax = nHistE > nHistP ? nHistE : nHistP;
  size_t recMax = (size_t)(E > NNZ ? E : NNZ);

  char* w = (char*)d_ws;
  auto alloc = [&](size_t bytes)->char*{ char* p=w; w += (bytes+255)&~255ull; return p; };
  int*    hist  = (int*)   alloc(4ull*(nHistMax+16));   // per-tile counts (preserved)
  int*    hist2 = (int*)   alloc(4ull*(nHistMax+16));   // scanned bases
  int*    bsum  = (int*)   alloc(4ull*4096);
  int*    rs    = (int*)   alloc(4ull*(N+1));
  int*    rsP   = (int*)   alloc(4ull*(P+1));
  int2*   rec   = (int2*)  alloc(8ull*recMax);   // edge CSR, then pool CSR
  int2*   tmp   = (int2*)  alloc(8ull*recMax);   // split staging; pooled[P][32] f32 after finalize_pool
  __half* xp16  = (__half*)alloc(2ull*32*N);
  float*  asrc  = (float*) alloc(8ull*N);
  float*  adst  = (float*) alloc(8ull*N);
  __half* hb16  = (__half*)alloc(2ull*32*N);     // f16 hidden state, reused across layers
  float*  weff  = (float*) alloc(256);
  float2* mattr = (float2*)alloc(8ull*N);
  float*  pooled = (float*)tmp;     // alias: tmp dead after finalize_pool (P*32*4 = 25.6MB == 8*NNZ)

  int gN = (N+TPB-1)/TPB;

  // ---- edge CSR via deterministic split (LDS-staged scatter, single-pass finalize) ----
  k_split_hist<<<T_E,STPB,0,stream>>>(dst, E, 8, T_E, hist, NBC_E);
  int nbE = (nHistE+1023)/1024;
  k_scan_tile<<<nbE,TPB,0,stream>>>(hist, hist2, bsum, nHistE);
  k_scan_small<<<1,TPB,0,stream>>>(bsum, nbE);
  k_scan_add<<<(nHistE+TPB-1)/TPB,TPB,0,stream>>>(hist2, bsum, nHistE, E);
  k_split_scatter_edges<<<T_E,STPB,0,stream>>>(src, dst, eattr, E, T_E, hist, hist2, tmp, NBC_E);
  k_finalize_edges<<<NBC_E,STPB,0,stream>>>(tmp, hist2, T_E, E, N, rs, rec);
  int gmt = (N + TPB/4 - 1)/(TPB/4);
  k_mattr<<<gmt,TPB,0,stream>>>(rec, rs, mattr, N);

  k_weff<<<1,64,0,stream>>>((const float*)d_in[12], (const float*)d_in[13],
                            (const float*)d_in[18], (const float*)d_in[19],
                            (const float*)d_in[24], (const float*)d_in[25], weff);

  // ---- layer 1 ----
  k_node_pre1<<<gN,TPB,0,stream>>>(group_ids, ord, emb,
      (const float*)d_in[9], (const float*)d_in[10], (const float*)d_in[11],
      xp16, asrc, adst, N);
  int gagg = (N+15)/16;
  k_agg<<<gagg,TPB,0,stream>>>(xp16, asrc, adst, rs, rec, mattr, weff+0,
      (const float*)d_in[14], hb16, N);
  // ---- layer 2 ----
  k_node_pre16<<<gN,TPB,0,stream>>>(hb16,
      (const float*)d_in[15], (const float*)d_in[16], (const float*)d_in[17],
      xp16, asrc, adst, N);
  k_agg<<<gagg,TPB,0,stream>>>(xp16, asrc, adst, rs, rec, mattr, weff+4,
      (const float*)d_in[20], hb16, N);
  // ---- layer 3 ----
  k_node_pre16<<<gN,TPB,0,stream>>>(hb16,
      (const float*)d_in[21], (const float*)d_in[22], (const float*)d_in[23],
      xp16, asrc, adst, N);
  k_agg<<<gagg,TPB,0,stream>>>(xp16, asrc, adst, rs, rec, mattr, weff+8,
      (const float*)d_in[26], hb16, N);

  // ---- pool CSR via same split ----
  k_split_hist<<<T_P,STPB,0,stream>>>(prow, NNZ, 9, T_P, hist, NBC_P);
  int nbP = (nHistP+1023)/1024;
  k_scan_tile<<<nbP,TPB,0,stream>>>(hist, hist2, bsum, nHistP);
  k_scan_small<<<1,TPB,0,stream>>>(bsum, nbP);
  k_scan_add<<<(nHistP+TPB-1)/TPB,TPB,0,stream>>>(hist2, bsum, nHistP, NNZ);
  k_split_scatter_pool<<<T_P,STPB,0,stream>>>(prow, pcol, pval, NNZ, T_P, hist, hist2, tmp, NBC_P);
  k_finalize_pool<<<NBC_P,STPB,0,stream>>>(tmp, hist2, T_P, NNZ, P, rsP, rec);

  // ---- pooling (quad/row) + MLP head (thread/row) ----
  int gpq = (P + TPB/4 - 1)/(TPB/4);
  k_pool_q<<<gpq,TPB,0,stream>>>(hb16, rsP, rec, pooled, P);
  k_head<<<(P+TPB-1)/TPB,TPB,0,stream>>>(pooled,
      head_w1, head_b1, head_w2, head_b2, (float*)d_out, P);
}

// Round 19
// 377.630 us; speedup vs baseline: 1.0689x; 1.0689x over previous
//
#include <hip/hip_runtime.h>
#include <hip/hip_fp16.h>

#define TPB 256
#define STPB 1024  // wide-block size for streaming kernels
#define TILE 8192  // items per split tile
#define FCAP 9216  // finalize LDS span capacity

__device__ __forceinline__ float leaky02(float x){ return x > 0.f ? x : 0.2f*x; }
__device__ __forceinline__ unsigned pack_h2(float a, float b){
  return (unsigned)__half_as_ushort(__float2half_rn(a)) |
         ((unsigned)__half_as_ushort(__float2half_rn(b)) << 16);
}

// ---------------- hierarchical exclusive scan (out-of-place: counts preserved) ----------------
__global__ void k_scan_tile(const int* __restrict__ in, int* __restrict__ out,
                            int* __restrict__ bsum, int n) {
  __shared__ int sh[TPB];
  int t = threadIdx.x;
  int base = blockIdx.x * (TPB*4) + t*4;
  int v0=0,v1=0,v2=0,v3=0;
  if (base+0 < n) v0 = in[base+0];
  if (base+1 < n) v1 = in[base+1];
  if (base+2 < n) v2 = in[base+2];
  if (base+3 < n) v3 = in[base+3];
  int tsum = v0+v1+v2+v3;
  sh[t] = tsum; __syncthreads();
  for (int off=1; off<TPB; off<<=1){
    int x = (t>=off) ? sh[t-off] : 0;
    __syncthreads();
    sh[t] += x;
    __syncthreads();
  }
  int incl = sh[t];
  int excl = incl - tsum;
  if (t == TPB-1) bsum[blockIdx.x] = incl;
  int run = excl;
  if (base+0 < n){ out[base+0] = run; run += v0; }
  if (base+1 < n){ out[base+1] = run; run += v1; }
  if (base+2 < n){ out[base+2] = run; run += v2; }
  if (base+3 < n){ out[base+3] = run; run += v3; }
}

__global__ void k_scan_small(int* __restrict__ a, int n) {
  __shared__ int sh[TPB];
  __shared__ int carry;
  int t = threadIdx.x;
  if (t==0) carry = 0;
  __syncthreads();
  for (int base=0; base<n; base+=TPB){
    int v = (base+t < n) ? a[base+t] : 0;
    sh[t] = v; __syncthreads();
    for (int off=1; off<TPB; off<<=1){
      int x = (t>=off)? sh[t-off]:0; __syncthreads();
      sh[t]+=x; __syncthreads();
    }
    int c0 = carry;
    if (base+t < n) a[base+t] = c0 + sh[t] - v;
    int tot = sh[TPB-1];
    __syncthreads();
    if (t==0) carry = c0 + tot;
    __syncthreads();
  }
}

__global__ void k_scan_add(int* __restrict__ out, const int* __restrict__ bsum,
                           int n, int total) {
  int i = blockIdx.x*TPB + threadIdx.x;
  if (i < n) out[i] += bsum[i >> 10];
  if (i == 0) out[n] = total;
}

// ---------------- split phase 1: per-tile histogram (LDS only) ----------------
__global__ __launch_bounds__(STPB) void k_split_hist(
    const int* __restrict__ key, int n, int shift, int T,
    int* __restrict__ hist, int nbc){
  __shared__ int cnt[512];
  int b = blockIdx.x, t = threadIdx.x;
  for (int k=t;k<nbc;k+=STPB) cnt[k]=0;
  __syncthreads();
  int i0 = b*TILE, end = min(n, i0+TILE);
  for (int i=i0+t; i<end; i+=STPB) atomicAdd(&cnt[key[i]>>shift], 1);
  __syncthreads();
  for (int k=t;k<nbc;k+=STPB) hist[(size_t)k*T + b] = cnt[k];
}

// ---- split phase 2: LDS-staged scatter; counts from hist, bases from hist2 ----
__global__ __launch_bounds__(STPB) void k_split_scatter_edges(
    const int* __restrict__ src, const int* __restrict__ dst,
    const float* __restrict__ eattr, int E, int T,
    const int* __restrict__ hist, const int* __restrict__ hist2,
    int2* __restrict__ tmp, int nbc){
  __shared__ int lcur[512];
  __shared__ int lbase[512];
  __shared__ int gbase[512];
  __shared__ int sh[256];
  __shared__ int carry_s;
  __shared__ int2 buf[TILE];       // 64 KB
  int b = blockIdx.x, t = threadIdx.x;
  if (t < 512){
    int c = (t < nbc) ? hist[(size_t)t*T + b] : 0;
    lcur[t] = c;
    gbase[t] = (t < nbc) ? hist2[(size_t)t*T + b] : 0;
  }
  __syncthreads();
  int v0 = 0;
  if (t < 256){ v0 = lcur[t]; sh[t] = v0; }
  __syncthreads();
  for (int off=1; off<256; off<<=1){
    int x = 0;
    if (t < 256 && t >= off) x = sh[t-off];
    __syncthreads();
    if (t < 256) sh[t] += x;
    __syncthreads();
  }
  if (t < 256) lbase[t] = sh[t] - v0;
  if (t == 255) carry_s = sh[255];
  __syncthreads();
  int v1 = 0;
  if (t < 256){ v1 = lcur[256+t]; sh[t] = v1; }
  __syncthreads();
  for (int off=1; off<256; off<<=1){
    int x = 0;
    if (t < 256 && t >= off) x = sh[t-off];
    __syncthreads();
    if (t < 256) sh[t] += x;
    __syncthreads();
  }
  if (t < 256) lbase[256+t] = carry_s + sh[t] - v1;
  __syncthreads();
  if (t < 512) lcur[t] = lbase[t];
  __syncthreads();
  int i0 = b*TILE, end = min(E, i0+TILE);
  for (int i=i0+t; i<end; i+=STPB){
    int d = dst[i];
    int k = d>>8;
    int pos = atomicAdd(&lcur[k], 1);
    float2 ea = ((const float2*)eattr)[i];
    buf[pos] = make_int2(src[i] | ((d & 255)<<17), (int)pack_h2(ea.x, ea.y));
  }
  __syncthreads();
  int wave = t >> 6, lane = t & 63;
  for (int k=wave; k<nbc; k+=STPB/64){
    int s = lbase[k];
    int c = lcur[k] - s;
    int g = gbase[k];
    for (int i=lane; i<c; i+=64) tmp[g+i] = buf[s+i];
  }
}

__global__ __launch_bounds__(STPB) void k_split_scatter_pool(
    const int* __restrict__ rows, const int* __restrict__ cols,
    const float* __restrict__ vals, int n, int T,
    const int* __restrict__ hist, const int* __restrict__ hist2,
    int2* __restrict__ tmp, int nbc){
  __shared__ int lcur[512];
  __shared__ int lbase[512];
  __shared__ int gbase[512];
  __shared__ int sh[256];
  __shared__ int carry_s;
  __shared__ int2 buf[TILE];       // 64 KB
  int b = blockIdx.x, t = threadIdx.x;
  if (t < 512){
    int c = (t < nbc) ? hist[(size_t)t*T + b] : 0;
    lcur[t] = c;
    gbase[t] = (t < nbc) ? hist2[(size_t)t*T + b] : 0;
  }
  __syncthreads();
  int v0 = 0;
  if (t < 256){ v0 = lcur[t]; sh[t] = v0; }
  __syncthreads();
  for (int off=1; off<256; off<<=1){
    int x = 0;
    if (t < 256 && t >= off) x = sh[t-off];
    __syncthreads();
    if (t < 256) sh[t] += x;
    __syncthreads();
  }
  if (t < 256) lbase[t] = sh[t] - v0;
  if (t == 255) carry_s = sh[255];
  __syncthreads();
  int v1 = 0;
  if (t < 256){ v1 = lcur[256+t]; sh[t] = v1; }
  __syncthreads();
  for (int off=1; off<256; off<<=1){
    int x = 0;
    if (t < 256 && t >= off) x = sh[t-off];
    __syncthreads();
    if (t < 256) sh[t] += x;
    __syncthreads();
  }
  if (t < 256) lbase[256+t] = carry_s + sh[t] - v1;
  __syncthreads();
  if (t < 512) lcur[t] = lbase[t];
  __syncthreads();
  int i0 = b*TILE, end = min(n, i0+TILE);
  for (int i=i0+t; i<end; i+=STPB){
    int r = rows[i];
    int k = r>>9;
    int pos = atomicAdd(&lcur[k], 1);
    buf[pos] = make_int2(cols[i] | ((r & 511)<<17), __float_as_int(vals[i]));
  }
  __syncthreads();
  int wave = t >> 6, lane = t & 63;
  for (int k=wave; k<nbc; k+=STPB/64){
    int s = lbase[k];
    int c = lcur[k] - s;
    int g = gbase[k];
    for (int i=lane; i<c; i+=64) tmp[g+i] = buf[s+i];
  }
}

// ---- finalize edges: single-pass via LDS span (fallback if oversize) ----
__global__ __launch_bounds__(STPB) void k_finalize_edges(
    const int2* __restrict__ tmp, const int* __restrict__ hist2, int T, int E,
    int N, int* __restrict__ rs, int2* __restrict__ rec){
  __shared__ int cnt[256];
  __shared__ int sh[256];
  __shared__ int2 fbuf[FCAP];      // 72 KB
  int b = blockIdx.x, t = threadIdx.x;
  int base = hist2[(size_t)b*T];
  int endv = (b+1 < (int)gridDim.x) ? hist2[(size_t)(b+1)*T] : E;
  int size = endv - base;
  bool fits = (size <= FCAP);
  if (t < 256) cnt[t] = 0;
  __syncthreads();
  if (fits){
    for (int i=t; i<size; i+=STPB) fbuf[i] = tmp[base+i];
    __syncthreads();
    for (int i=t; i<size; i+=STPB) atomicAdd(&cnt[(((unsigned)fbuf[i].x)>>17)&255], 1);
  } else {
    for (int i=t; i<size; i+=STPB) atomicAdd(&cnt[(((unsigned)tmp[base+i].x)>>17)&255], 1);
  }
  __syncthreads();
  int v = 0;
  if (t < 256){ v = cnt[t]; sh[t] = v; }
  __syncthreads();
  for (int off=1; off<256; off<<=1){
    int x = 0;
    if (t < 256 && t >= off) x = sh[t-off];
    __syncthreads();
    if (t < 256) sh[t] += x;
    __syncthreads();
  }
  if (t < 256){
    int excl = sh[t] - v;
    int d = (b<<8)+t;
    if (d<=N) rs[d] = base + excl;
    cnt[t] = excl;
  }
  __syncthreads();
  if (fits){
    for (int i=t; i<size; i+=STPB){
      int2 q = fbuf[i];
      int k = (((unsigned)q.x)>>17)&255;
      int p = atomicAdd(&cnt[k],1);
      rec[base+p] = make_int2(q.x & 0x1FFFF, q.y);
    }
  } else {
    for (int i=t; i<size; i+=STPB){
      int2 q = tmp[base+i];
      int k = (((unsigned)q.x)>>17)&255;
      int p = atomicAdd(&cnt[k],1);
      rec[base+p] = make_int2(q.x & 0x1FFFF, q.y);
    }
  }
}

// ---- mattr: quad-per-node sweep over sorted CSR span (no atomics) ----
__global__ __launch_bounds__(TPB) void k_mattr(
    const int2* __restrict__ rec, const int* __restrict__ rs,
    float2* __restrict__ mattr, int N){
  int n = blockIdx.x*(TPB/4) + (threadIdx.x>>2);
  if (n >= N) return;
  int l4 = threadIdx.x & 3;
  int jb = rs[n], je = rs[n+1];
  float sx = 0.f, sy = 0.f;
  for (int j = jb + l4; j < je; j += 4){
    float2 ea = __half22float2(*(const __half2*)&rec[j].y);
    sx += ea.x; sy += ea.y;
  }
  sx += __shfl_xor(sx, 1); sx += __shfl_xor(sx, 2);
  sy += __shfl_xor(sy, 1); sy += __shfl_xor(sy, 2);
  if (l4 == 0){
    int cn = je - jb;
    float inv = 1.0f/(float)(cn > 0 ? cn : 1);
    mattr[n] = make_float2(sx*inv, sy*inv);
  }
}

// ---- finalize pool: single-pass via LDS span (fallback if oversize) ----
__global__ __launch_bounds__(STPB) void k_finalize_pool(
    const int2* __restrict__ tmp, const int* __restrict__ hist2, int T, int NNZ,
    int P, int* __restrict__ rs, int2* __restrict__ rec){
  __shared__ int cnt[512];
  __shared__ int sh[256];
  __shared__ int carry_s;
  __shared__ int2 fbuf[FCAP];      // 72 KB
  int b = blockIdx.x, t = threadIdx.x;
  int base = hist2[(size_t)b*T];
  int endv = (b+1 < (int)gridDim.x) ? hist2[(size_t)(b+1)*T] : NNZ;
  int size = endv - base;
  bool fits = (size <= FCAP);
  if (t < 512) cnt[t] = 0;
  __syncthreads();
  if (fits){
    for (int i=t;i<size;i+=STPB) fbuf[i] = tmp[base+i];
    __syncthreads();
    for (int i=t;i<size;i+=STPB) atomicAdd(&cnt[(((unsigned)fbuf[i].x)>>17)&511], 1);
  } else {
    for (int i=t;i<size;i+=STPB) atomicAdd(&cnt[(((unsigned)tmp[base+i].x)>>17)&511], 1);
  }
  __syncthreads();
  int excl0 = 0, excl1 = 0;
  int v0 = 0;
  if (t < 256){ v0 = cnt[t]; sh[t] = v0; }
  __syncthreads();
  for (int off=1; off<256; off<<=1){
    int x = 0;
    if (t < 256 && t >= off) x = sh[t-off];
    __syncthreads();
    if (t < 256) sh[t] += x;
    __syncthreads();
  }
  if (t < 256) excl0 = sh[t] - v0;
  if (t == 255) carry_s = sh[255];
  __syncthreads();
  int v1 = 0;
  if (t < 256){ v1 = cnt[256+t]; sh[t] = v1; }
  __syncthreads();
  for (int off=1; off<256; off<<=1){
    int x = 0;
    if (t < 256 && t >= off) x = sh[t-off];
    __syncthreads();
    if (t < 256) sh[t] += x;
    __syncthreads();
  }
  if (t < 256) excl1 = carry_s + sh[t] - v1;
  __syncthreads();
  if (t < 256){
    cnt[t] = excl0; cnt[256+t] = excl1;
    int r0 = (b<<9)+t;
    if (r0<=P) rs[r0] = base+excl0;
    int r1 = r0+256;
    if (r1<=P) rs[r1] = base+excl1;
  }
  __syncthreads();
  if (fits){
    for (int i=t;i<size;i+=STPB){
      int2 q = fbuf[i];
      int k = (((unsigned)q.x)>>17)&511;
      int p = atomicAdd(&cnt[k],1);
      rec[base+p] = make_int2(q.x & 0x1FFFF, q.y);
    }
  } else {
    for (int i=t;i<size;i+=STPB){
      int2 q = tmp[base+i];
      int k = (((unsigned)q.x)>>17)&511;
      int p = atomicAdd(&cnt[k],1);
      rec[base+p] = make_int2(q.x & 0x1FFFF, q.y);
    }
  }
}

// ---------------- effective edge weights: weff[l*4 + h*2 + {0,1}] ----------------
__global__ void k_weff(const float* __restrict__ ew1, const float* __restrict__ ae1,
                       const float* __restrict__ ew2, const float* __restrict__ ae2,
                       const float* __restrict__ ew3, const float* __restrict__ ae3,
                       float* __restrict__ weff){
  int t = threadIdx.x;
  if (t >= 6) return;
  int l = t>>1, h = t&1;
  const float* ew = l==0?ew1:(l==1?ew2:ew3);
  const float* ae = l==0?ae1:(l==1?ae2:ae3);
  float w0=0.f, w1=0.f;
  for (int c=0;c<16;c++){
    float a = ae[h*16+c];
    w0 += ew[h*16+c]*a;
    w1 += ew[32+h*16+c]*a;
  }
  weff[l*4+h*2]   = w0;
  weff[l*4+h*2+1] = w1;
}

// ---- node transform, QUAD per node: lane computes 8 channels ----
__global__ __launch_bounds__(TPB) void k_node_pre1(
    const int* __restrict__ gid, const float* __restrict__ ord, const float* __restrict__ emb,
    const float* __restrict__ lin_w, const float* __restrict__ att_src, const float* __restrict__ att_dst,
    __half* __restrict__ xp16, float* __restrict__ asrc, float* __restrict__ adst, int N){
  __shared__ float W[20*32];
  __shared__ float As[32], Ad[32];
  for (int i=threadIdx.x; i<20*32; i+=TPB) W[i]=lin_w[i];
  if (threadIdx.x < 32){ As[threadIdx.x]=att_src[threadIdx.x]; Ad[threadIdx.x]=att_dst[threadIdx.x]; }
  __syncthreads();
  int n = blockIdx.x*(TPB/4) + (threadIdx.x>>2);
  if (n>=N) return;
  int l4 = threadIdx.x & 3;
  int c0 = l4*8;
  float x[20];
  int g = gid[n];
  const float4* e4 = (const float4*)(emb + (size_t)g*16);
  #pragma unroll
  for (int q=0;q<4;q++){ float4 v=e4[q]; x[4*q]=v.x; x[4*q+1]=v.y; x[4*q+2]=v.z; x[4*q+3]=v.w; }
  float4 o4 = ((const float4*)ord)[n];
  x[16]=o4.x; x[17]=o4.y; x[18]=o4.z; x[19]=o4.w;
  float acc[8];
  #pragma unroll
  for (int c=0;c<8;c++) acc[c]=0.f;
  #pragma unroll
  for (int k=0;k<20;k++){
    float xk=x[k];
    #pragma unroll
    for (int c=0;c<8;c++) acc[c] += xk*W[k*32+c0+c];
  }
  float s=0.f, d=0.f;
  #pragma unroll
  for (int c=0;c<8;c++){ s += acc[c]*As[c0+c]; d += acc[c]*Ad[c0+c]; }
  s += __shfl_xor(s,1); d += __shfl_xor(d,1);
  if ((l4&1)==0){
    int h = l4>>1;
    asrc[2*n+h]=s; adst[2*n+h]=d;
  }
  ((uint4*)(xp16 + (size_t)n*32))[l4] =
    make_uint4(pack_h2(acc[0],acc[1]), pack_h2(acc[2],acc[3]),
               pack_h2(acc[4],acc[5]), pack_h2(acc[6],acc[7]));
}

__global__ __launch_bounds__(TPB) void k_node_pre16(
    const __half* __restrict__ hin,
    const float* __restrict__ lin_w, const float* __restrict__ att_src, const float* __restrict__ att_dst,
    __half* __restrict__ xp16, float* __restrict__ asrc, float* __restrict__ adst, int N){
  __shared__ float W[32*32];
  __shared__ float As[32], Ad[32];
  for (int i=threadIdx.x; i<1024; i+=TPB) W[i]=lin_w[i];
  if (threadIdx.x < 32){ As[threadIdx.x]=att_src[threadIdx.x]; Ad[threadIdx.x]=att_dst[threadIdx.x]; }
  __syncthreads();
  int n = blockIdx.x*(TPB/4) + (threadIdx.x>>2);
  if (n>=N) return;
  int l4 = threadIdx.x & 3;
  int c0 = l4*8;
  float x[32];
  const uint4* hi = (const uint4*)(hin + (size_t)n*32);
  #pragma unroll
  for (int q=0;q<4;q++){
    uint4 u = hi[q];
    float2 f;
    f=__half22float2(*(const __half2*)&u.x); x[q*8+0]=f.x; x[q*8+1]=f.y;
    f=__half22float2(*(const __half2*)&u.y); x[q*8+2]=f.x; x[q*8+3]=f.y;
    f=__half22float2(*(const __half2*)&u.z); x[q*8+4]=f.x; x[q*8+5]=f.y;
    f=__half22float2(*(const __half2*)&u.w); x[q*8+6]=f.x; x[q*8+7]=f.y;
  }
  float acc[8];
  #pragma unroll
  for (int c=0;c<8;c++) acc[c]=0.f;
  #pragma unroll
  for (int k=0;k<32;k++){
    float xk=x[k];
    #pragma unroll
    for (int c=0;c<8;c++) acc[c] += xk*W[k*32+c0+c];
  }
  float s=0.f, d=0.f;
  #pragma unroll
  for (int c=0;c<8;c++){ s += acc[c]*As[c0+c]; d += acc[c]*Ad[c0+c]; }
  s += __shfl_xor(s,1); d += __shfl_xor(d,1);
  if ((l4&1)==0){
    int h = l4>>1;
    asrc[2*n+h]=s; adst[2*n+h]=d;
  }
  ((uint4*)(xp16 + (size_t)n*32))[l4] =
    make_uint4(pack_h2(acc[0],acc[1]), pack_h2(acc[2],acc[3]),
               pack_h2(acc[4],acc[5]), pack_h2(acc[6],acc[7]));
}

// ---- GAT aggregation: 4 nodes/wave x 4 quads/node, 4-deep pipeline, f16 output ----
__global__ __launch_bounds__(TPB) void k_agg(
    const __half* __restrict__ xp16, const float* __restrict__ asrc, const float* __restrict__ adst,
    const int* __restrict__ rs, const int2* __restrict__ rec,
    const float2* __restrict__ mattr,
    const float* __restrict__ weff_l,
    const float* __restrict__ bias, __half* __restrict__ hout16, int N)
{
  int lane = threadIdx.x & 63;
  int node_slot = lane >> 4;          // 4 nodes per wave
  int n = blockIdx.x*16 + (threadIdx.x>>6)*4 + node_slot;
  if (n >= N) return;                 // whole 16-lane group exits together
  int sub = (lane >> 2) & 3;          // 4 quads per node
  int l4  = lane & 3;                 // owns channels l4*8 .. l4*8+7
  int h   = l4 >> 1;
  float2 wv = ((const float2*)weff_l)[h];
  float adn = adst[2*n+h];
  float ax0=0,ay0=0,ax1=0,ay1=0,ax2=0,ay2=0,ax3=0,ay3=0;
  float den=0.f;
  int jb = rs[n], je = rs[n+1];
  int j = jb + sub;
  for (; j + 12 < je; j += 16){
    int2 r1 = rec[j];
    int2 r2 = rec[j+4];
    int2 r3 = rec[j+8];
    int2 r4 = rec[j+12];
    uint4 u1 = ((const uint4*)(xp16 + (size_t)r1.x*32))[l4];
    uint4 u2 = ((const uint4*)(xp16 + (size_t)r2.x*32))[l4];
    uint4 u3 = ((const uint4*)(xp16 + (size_t)r3.x*32))[l4];
    uint4 u4 = ((const uint4*)(xp16 + (size_t)r4.x*32))[l4];
    float as1 = asrc[2*r1.x+h];
    float as2 = asrc[2*r2.x+h];
    float as3 = asrc[2*r3.x+h];
    float as4 = asrc[2*r4.x+h];
    float2 e1 = __half22float2(*(const __half2*)&r1.y);
    float2 e2 = __half22float2(*(const __half2*)&r2.y);
    float2 e3 = __half22float2(*(const __half2*)&r3.y);
    float2 e4 = __half22float2(*(const __half2*)&r4.y);
    float p1 = __expf(leaky02(as1 + adn + e1.x*wv.x + e1.y*wv.y));
    float p2 = __expf(leaky02(as2 + adn + e2.x*wv.x + e2.y*wv.y));
    float p3 = __expf(leaky02(as3 + adn + e3.x*wv.x + e3.y*wv.y));
    float p4 = __expf(leaky02(as4 + adn + e4.x*wv.x + e4.y*wv.y));
    float2 f;
    f=__half22float2(*(const __half2*)&u1.x); ax0+=p1*f.x; ay0+=p1*f.y;
    f=__half22float2(*(const __half2*)&u1.y); ax1+=p1*f.x; ay1+=p1*f.y;
    f=__half22float2(*(const __half2*)&u1.z); ax2+=p1*f.x; ay2+=p1*f.y;
    f=__half22float2(*(const __half2*)&u1.w); ax3+=p1*f.x; ay3+=p1*f.y;
    f=__half22float2(*(const __half2*)&u2.x); ax0+=p2*f.x; ay0+=p2*f.y;
    f=__half22float2(*(const __half2*)&u2.y); ax1+=p2*f.x; ay1+=p2*f.y;
    f=__half22float2(*(const __half2*)&u2.z); ax2+=p2*f.x; ay2+=p2*f.y;
    f=__half22float2(*(const __half2*)&u2.w); ax3+=p2*f.x; ay3+=p2*f.y;
    f=__half22float2(*(const __half2*)&u3.x); ax0+=p3*f.x; ay0+=p3*f.y;
    f=__half22float2(*(const __half2*)&u3.y); ax1+=p3*f.x; ay1+=p3*f.y;
    f=__half22float2(*(const __half2*)&u3.z); ax2+=p3*f.x; ay2+=p3*f.y;
    f=__half22float2(*(const __half2*)&u3.w); ax3+=p3*f.x; ay3+=p3*f.y;
    f=__half22float2(*(const __half2*)&u4.x); ax0+=p4*f.x; ay0+=p4*f.y;
    f=__half22float2(*(const __half2*)&u4.y); ax1+=p4*f.x; ay1+=p4*f.y;
    f=__half22float2(*(const __half2*)&u4.z); ax2+=p4*f.x; ay2+=p4*f.y;
    f=__half22float2(*(const __half2*)&u4.w); ax3+=p4*f.x; ay3+=p4*f.y;
    den += p1 + p2 + p3 + p4;
  }
  for (; j < je; j += 4){
    int2 r1 = rec[j];
    uint4 u1 = ((const uint4*)(xp16 + (size_t)r1.x*32))[l4];
    float as1 = asrc[2*r1.x+h];
    float2 e1 = __half22float2(*(const __half2*)&r1.y);
    float p1 = __expf(leaky02(as1 + adn + e1.x*wv.x + e1.y*wv.y));
    float2 f;
    f=__half22float2(*(const __half2*)&u1.x); ax0+=p1*f.x; ay0+=p1*f.y;
    f=__half22float2(*(const __half2*)&u1.y); ax1+=p1*f.x; ay1+=p1*f.y;
    f=__half22float2(*(const __half2*)&u1.z); ax2+=p1*f.x; ay2+=p1*f.y;
    f=__half22float2(*(const __half2*)&u1.w); ax3+=p1*f.x; ay3+=p1*f.y;
    den += p1;
  }
  #pragma unroll
  for (int m=4; m<16; m<<=1){
    ax0+=__shfl_xor(ax0,m); ay0+=__shfl_xor(ay0,m);
    ax1+=__shfl_xor(ax1,m); ay1+=__shfl_xor(ay1,m);
    ax2+=__shfl_xor(ax2,m); ay2+=__shfl_xor(ay2,m);
    ax3+=__shfl_xor(ax3,m); ay3+=__shfl_xor(ay3,m);
    den+=__shfl_xor(den,m);
  }
  if (sub == 0){
    float2 ma = mattr[n];
    float al = leaky02(asrc[2*n+h] + adn + ma.x*wv.x + ma.y*wv.y);
    float p = __expf(al);
    uint4 u = ((const uint4*)(xp16 + (size_t)n*32))[l4];
    float2 f0 = __half22float2(*(const __half2*)&u.x);
    float2 f1 = __half22float2(*(const __half2*)&u.y);
    float2 f2 = __half22float2(*(const __half2*)&u.z);
    float2 f3 = __half22float2(*(const __half2*)&u.w);
    ax0 += p*f0.x; ay0 += p*f0.y;
    ax1 += p*f1.x; ay1 += p*f1.y;
    ax2 += p*f2.x; ay2 += p*f2.y;
    ax3 += p*f3.x; ay3 += p*f3.y;
    den += p;
    float dinv = 1.0f/(den + 1e-16f);
    float4 b0 = ((const float4*)bias)[l4*2];
    float4 b1 = ((const float4*)bias)[l4*2+1];
    float o0 = fmaxf(ax0*dinv + b0.x, 0.f);
    float o1 = fmaxf(ay0*dinv + b0.y, 0.f);
    float o2 = fmaxf(ax1*dinv + b0.z, 0.f);
    float o3 = fmaxf(ay1*dinv + b0.w, 0.f);
    float o4 = fmaxf(ax2*dinv + b1.x, 0.f);
    float o5 = fmaxf(ay2*dinv + b1.y, 0.f);
    float o6 = fmaxf(ax3*dinv + b1.z, 0.f);
    float o7 = fmaxf(ay3*dinv + b1.w, 0.f);
    ((uint4*)(hout16 + (size_t)n*32))[l4] =
      make_uint4(pack_h2(o0,o1), pack_h2(o2,o3), pack_h2(o4,o5), pack_h2(o6,o7));
  }
}

// ---------------- pooling: QUAD per row, 4-deep pipelined serial accumulate ----------------
__global__ __launch_bounds__(TPB) void k_pool_q(
    const __half* __restrict__ h3, const int* __restrict__ rsP,
    const int2* __restrict__ rec, float* __restrict__ pooled, int P){
  int p = blockIdx.x*(TPB/4) + (threadIdx.x>>2);
  if (p >= P) return;
  int l4 = threadIdx.x & 3;
  float ax0=0,ay0=0,ax1=0,ay1=0,ax2=0,ay2=0,ax3=0,ay3=0;
  int jb = rsP[p], je = rsP[p+1];
  int j = jb;
  for (; j+3 < je; j += 4){
    int2 q1 = rec[j];
    int2 q2 = rec[j+1];
    int2 q3 = rec[j+2];
    int2 q4 = rec[j+3];
    uint4 u1 = ((const uint4*)(h3 + (size_t)q1.x*32))[l4];
    uint4 u2 = ((const uint4*)(h3 + (size_t)q2.x*32))[l4];
    uint4 u3 = ((const uint4*)(h3 + (size_t)q3.x*32))[l4];
    uint4 u4 = ((const uint4*)(h3 + (size_t)q4.x*32))[l4];
    float v1 = __int_as_float(q1.y);
    float v2 = __int_as_float(q2.y);
    float v3 = __int_as_float(q3.y);
    float v4 = __int_as_float(q4.y);
    float2 f;
    f=__half22float2(*(const __half2*)&u1.x); ax0+=v1*f.x; ay0+=v1*f.y;
    f=__half22float2(*(const __half2*)&u1.y); ax1+=v1*f.x; ay1+=v1*f.y;
    f=__half22float2(*(const __half2*)&u1.z); ax2+=v1*f.x; ay2+=v1*f.y;
    f=__half22float2(*(const __half2*)&u1.w); ax3+=v1*f.x; ay3+=v1*f.y;
    f=__half22float2(*(const __half2*)&u2.x); ax0+=v2*f.x; ay0+=v2*f.y;
    f=__half22float2(*(const __half2*)&u2.y); ax1+=v2*f.x; ay1+=v2*f.y;
    f=__half22float2(*(const __half2*)&u2.z); ax2+=v2*f.x; ay2+=v2*f.y;
    f=__half22float2(*(const __half2*)&u2.w); ax3+=v2*f.x; ay3+=v2*f.y;
    f=__half22float2(*(const __half2*)&u3.x); ax0+=v3*f.x; ay0+=v3*f.y;
    f=__half22float2(*(const __half2*)&u3.y); ax1+=v3*f.x; ay1+=v3*f.y;
    f=__half22float2(*(const __half2*)&u3.z); ax2+=v3*f.x; ay2+=v3*f.y;
    f=__half22float2(*(const __half2*)&u3.w); ax3+=v3*f.x; ay3+=v3*f.y;
    f=__half22float2(*(const __half2*)&u4.x); ax0+=v4*f.x; ay0+=v4*f.y;
    f=__half22float2(*(const __half2*)&u4.y); ax1+=v4*f.x; ay1+=v4*f.y;
    f=__half22float2(*(const __half2*)&u4.z); ax2+=v4*f.x; ay2+=v4*f.y;
    f=__half22float2(*(const __half2*)&u4.w); ax3+=v4*f.x; ay3+=v4*f.y;
  }
  for (; j < je; ++j){
    int2 q1 = rec[j];
    uint4 u1 = ((const uint4*)(h3 + (size_t)q1.x*32))[l4];
    float v1 = __int_as_float(q1.y);
    float2 f;
    f=__half22float2(*(const __half2*)&u1.x); ax0+=v1*f.x; ay0+=v1*f.y;
    f=__half22float2(*(const __half2*)&u1.y); ax1+=v1*f.x; ay1+=v1*f.y;
    f=__half22float2(*(const __half2*)&u1.z); ax2+=v1*f.x; ay2+=v1*f.y;
    f=__half22float2(*(const __half2*)&u1.w); ax3+=v1*f.x; ay3+=v1*f.y;
  }
  float4* o = (float4*)(pooled + (size_t)p*32);
  o[l4*2]   = make_float4(ax0,ay0,ax1,ay1);
  o[l4*2+1] = make_float4(ax2,ay2,ax3,ay3);
}

// ---------------- MLP head: thread per row ----------------
__global__ __launch_bounds__(TPB) void k_head(
    const float* __restrict__ pooled,
    const float* __restrict__ W1, const float* __restrict__ b1,
    const float* __restrict__ W2, const float* __restrict__ b2,
    float* __restrict__ out, int P){
  __shared__ float sW1[32*32];
  __shared__ float sb1[32], sW2[32];
  for (int i=threadIdx.x;i<1024;i+=TPB) sW1[i]=W1[i];
  if (threadIdx.x<32){ sb1[threadIdx.x]=b1[threadIdx.x]; sW2[threadIdx.x]=W2[threadIdx.x]; }
  __syncthreads();
  int p = blockIdx.x*TPB + threadIdx.x;
  if (p >= P) return;
  float x[32];
  const float4* pi = (const float4*)(pooled + (size_t)p*32);
  #pragma unroll
  for (int q=0;q<8;q++){ float4 v=pi[q]; x[4*q]=v.x; x[4*q+1]=v.y; x[4*q+2]=v.z; x[4*q+3]=v.w; }
  float r = 0.f;
  #pragma unroll
  for (int c=0;c<32;c++){
    float hh = sb1[c];
    #pragma unroll
    for (int k=0;k<32;k++) hh += x[k]*sW1[k*32+c];
    r += fmaxf(hh, 0.f) * sW2[c];
  }
  out[p] = r + b2[0];
}

// ---------------- launch ----------------
extern "C" void kernel_launch(void* const* d_in, const int* in_sizes, int n_in,
                              void* d_out, int out_size, void* d_ws, size_t ws_size,
                              hipStream_t stream){
  const int*   group_ids = (const int*)d_in[0];
  const float* ord       = (const float*)d_in[1];
  const int*   eidx      = (const int*)d_in[2];
  const float* eattr     = (const float*)d_in[3];
  const int*   prow      = (const int*)d_in[4];
  const int*   pcol      = (const int*)d_in[5];
  const float* pval      = (const float*)d_in[6];
  const float* emb       = (const float*)d_in[8];
  const float* head_w1   = (const float*)d_in[27];
  const float* head_b1   = (const float*)d_in[28];
  const float* head_w2   = (const float*)d_in[29];
  const float* head_b2   = (const float*)d_in[30];

  int N   = in_sizes[0];
  int E   = in_sizes[2]/2;
  int NNZ = in_sizes[4];
  int P   = out_size;

  const int* src = eidx;
  const int* dst = eidx + E;

  int NBC_E = (N+255)>>8;
  int T_E   = (E + TILE-1)/TILE;
  int nHistE = NBC_E*T_E;
  int NBC_P = (P+511)>>9;
  int T_P   = (NNZ + TILE-1)/TILE;
  int nHistP = NBC_P*T_P;
  int nHistMax = nHistE > nHistP ? nHistE : nHistP;
  size_t recMax = (size_t)(E > NNZ ? E : NNZ);

  char* w = (char*)d_ws;
  auto alloc = [&](size_t bytes)->char*{ char* p=w; w += (bytes+255)&~255ull; return p; };
  int*    hist  = (int*)   alloc(4ull*(nHistMax+16));   // per-tile counts (preserved)
  int*    hist2 = (int*)   alloc(4ull*(nHistMax+16));   // scanned bases
  int*    bsum  = (int*)   alloc(4ull*4096);
  int*    rs    = (int*)   alloc(4ull*(N+1));
  int*    rsP   = (int*)   alloc(4ull*(P+1));
  int2*   rec   = (int2*)  alloc(8ull*recMax);   // edge CSR, then pool CSR
  int2*   tmp   = (int2*)  alloc(8ull*recMax);   // split staging; pooled[P][32] f32 after finalize_pool
  __half* xp16  = (__half*)alloc(2ull*32*N);
  float*  asrc  = (float*) alloc(8ull*N);
  float*  adst  = (float*) alloc(8ull*N);
  __half* hb16  = (__half*)alloc(2ull*32*N);     // f16 hidden state, reused across layers
  float*  weff  = (float*) alloc(256);
  float2* mattr = (float2*)alloc(8ull*N);
  float*  pooled = (float*)tmp;     // alias: tmp dead after finalize_pool (P*32*4 = 25.6MB == 8*NNZ)

  // ---- edge CSR via deterministic split (LDS-staged scatter, single-pass finalize) ----
  k_split_hist<<<T_E,STPB,0,stream>>>(dst, E, 8, T_E, hist, NBC_E);
  int nbE = (nHistE+1023)/1024;
  k_scan_tile<<<nbE,TPB,0,stream>>>(hist, hist2, bsum, nHistE);
  k_scan_small<<<1,TPB,0,stream>>>(bsum, nbE);
  k_scan_add<<<(nHistE+TPB-1)/TPB,TPB,0,stream>>>(hist2, bsum, nHistE, E);
  k_split_scatter_edges<<<T_E,STPB,0,stream>>>(src, dst, eattr, E, T_E, hist, hist2, tmp, NBC_E);
  k_finalize_edges<<<NBC_E,STPB,0,stream>>>(tmp, hist2, T_E, E, N, rs, rec);
  int gmt = (N + TPB/4 - 1)/(TPB/4);
  k_mattr<<<gmt,TPB,0,stream>>>(rec, rs, mattr, N);

  k_weff<<<1,64,0,stream>>>((const float*)d_in[12], (const float*)d_in[13],
                            (const float*)d_in[18], (const float*)d_in[19],
                            (const float*)d_in[24], (const float*)d_in[25], weff);

  int gNq = (N + TPB/4 - 1)/(TPB/4);   // quad-per-node grid
  // ---- layer 1 ----
  k_node_pre1<<<gNq,TPB,0,stream>>>(group_ids, ord, emb,
      (const float*)d_in[9], (const float*)d_in[10], (const float*)d_in[11],
      xp16, asrc, adst, N);
  int gagg = (N+15)/16;
  k_agg<<<gagg,TPB,0,stream>>>(xp16, asrc, adst, rs, rec, mattr, weff+0,
      (const float*)d_in[14], hb16, N);
  // ---- layer 2 ----
  k_node_pre16<<<gNq,TPB,0,stream>>>(hb16,
      (const float*)d_in[15], (const float*)d_in[16], (const float*)d_in[17],
      xp16, asrc, adst, N);
  k_agg<<<gagg,TPB,0,stream>>>(xp16, asrc, adst, rs, rec, mattr, weff+4,
      (const float*)d_in[20], hb16, N);
  // ---- layer 3 ----
  k_node_pre16<<<gNq,TPB,0,stream>>>(hb16,
      (const float*)d_in[21], (const float*)d_in[22], (const float*)d_in[23],
      xp16, asrc, adst, N);
  k_agg<<<gagg,TPB,0,stream>>>(xp16, asrc, adst, rs, rec, mattr, weff+8,
      (const float*)d_in[26], hb16, N);

  // ---- pool CSR via same split ----
  k_split_hist<<<T_P,STPB,0,stream>>>(prow, NNZ, 9, T_P, hist, NBC_P);
  int nbP = (nHistP+1023)/1024;
  k_scan_tile<<<nbP,TPB,0,stream>>>(hist, hist2, bsum, nHistP);
  k_scan_small<<<1,TPB,0,stream>>>(bsum, nbP);
  k_scan_add<<<(nHistP+TPB-1)/TPB,TPB,0,stream>>>(hist2, bsum, nHistP, NNZ);
  k_split_scatter_pool<<<T_P,STPB,0,stream>>>(prow, pcol, pval, NNZ, T_P, hist, hist2, tmp, NBC_P);
  k_finalize_pool<<<NBC_P,STPB,0,stream>>>(tmp, hist2, T_P, NNZ, P, rsP, rec);

  // ---- pooling (quad/row) + MLP head (thread/row) ----
  int gpq = (P + TPB/4 - 1)/(TPB/4);
  k_pool_q<<<gpq,TPB,0,stream>>>(hb16, rsP, rec, pooled, P);
  k_head<<<(P+TPB-1)/TPB,TPB,0,stream>>>(pooled,
      head_w1, head_b1, head_w2, head_b2, (float*)d_out, P);
}